// Round 9
// baseline (752.449 us; speedup 1.0000x reference)
//
#include <hip/hip_runtime.h>
#include <math.h>

#define D 768
#define DF4 192      // D/4
#define SEQ 128
#define TN 256       // docs per block tile (4 per lane)
#define DLANE 4
#define NCHUNK 48    // 16 floats (4 f4) per doc per chunk
#define NBK 64       // top-k blocks per row
#define TOPK 10

#define AS1 __attribute__((address_space(1)))
#define AS3 __attribute__((address_space(3)))

// ---------------- K1: mean over sequence ----------------
__global__ __launch_bounds__(256) void k_mean(const float* __restrict__ q,
                                              float* __restrict__ qmean) {
  int d = blockIdx.x * 256 + threadIdx.x;   // grid.x = 3 -> 768
  int b = blockIdx.y;
  if (d >= D) return;
  const float* p = q + (long)b * SEQ * D + d;
  float s = 0.f;
  #pragma unroll 8
  for (int i = 0; i < SEQ; ++i) s += p[(long)i * D];
  qmean[b * D + d] = s * (1.0f / SEQ);
}

// ---------------- K2: projection + bias + L2 normalize ----------------
__global__ __launch_bounds__(256) void k_proj(const float* __restrict__ qmean,
                                              const float* __restrict__ W,
                                              const float* __restrict__ bias,
                                              float* __restrict__ qnorm) {
  __shared__ float4 qm[DF4];
  __shared__ float red[256];
  int b = blockIdx.x, t = threadIdx.x;
  for (int i = t; i < DF4; i += 256) qm[i] = ((const float4*)qmean)[b * DF4 + i];
  __syncthreads();
  float myout[3];
  #pragma unroll
  for (int i = 0; i < 3; ++i) {
    int j = t + i * 256;
    const float4* wr = (const float4*)W + (long)j * DF4;
    float a0 = 0.f, a1 = 0.f, a2 = 0.f, a3 = 0.f;
    for (int kk = 0; kk < DF4; ++kk) {
      float4 w = wr[kk]; float4 qv = qm[kk];
      a0 = fmaf(w.x, qv.x, a0); a1 = fmaf(w.y, qv.y, a1);
      a2 = fmaf(w.z, qv.z, a2); a3 = fmaf(w.w, qv.w, a3);
    }
    myout[i] = (a0 + a1) + (a2 + a3) + bias[j];
  }
  float ss = myout[0]*myout[0] + myout[1]*myout[1] + myout[2]*myout[2];
  red[t] = ss;
  __syncthreads();
  for (int h = 128; h > 0; h >>= 1) {
    if (t < h) red[t] += red[t + h];
    __syncthreads();
  }
  float rn = 1.0f / fmaxf(sqrtf(red[0]), 1e-12f);
  #pragma unroll
  for (int i = 0; i < 3; ++i) {
    int j = t + i * 256;
    qnorm[b * D + j] = myout[i] * rn;
  }
}

// ---------------- K3: cosine scores (the big one) ----------------
// r9. Evidence: r6 (590us, 4 blk/CU) vs r8 (700us, 3 blk/CU) — overlap-
// limited (pipes at 39-60%), occupancy is the measured lever; q-broadcast
// reads are 32/56 of LDS traffic.
//  - q via BATCHED SGPR loads, 2-stage prefetch: 8 s_load-x4 per slot issued
//    one slot ahead, consumed as SGPR operands in v_fmac (1 SGPR/inst ok).
//    Unlike r5 (256 fine-grain s_loads interleaved -> per-use lgkmcnt(0)
//    drains), batching+lookahead shares the single lgkmcnt join with the
//    doc ds_reads we need anyway. Kills all q LDS reads (56 -> 16 per
//    thread-chunk) and frees sQ.
//  - TN=256/DLANE=4, sD only = 32 KB -> 5 blocks/CU resident; 1954 blocks
//    (tail 1.048 vs r8's 1.18).
//  - Staging (r8-proven): 64 B/doc chunks, issue = 16 docs x 64 B contiguous
//    segments; slot involution ((doc>>1)&3 XOR) on source + read.
//  - Depth-2 single-barrier pipeline (r8): stage c+1 at top of compute-c;
//    __syncthreads' vmcnt(0) drains loads issued a full compute-phase ago.
//  - Natural VGPR alloc (launch_bounds(256,{2,3,4}) pins 64 and spills:
//    r1/r3/r4 measured).
__global__ __launch_bounds__(256) __attribute__((amdgpu_waves_per_eu(2, 4)))
void k_scores(const float* __restrict__ docs,
              const float* __restrict__ qn,
              float* __restrict__ outS, int N) {
  __shared__ float4 sD[2][TN][4];   // 2 x 16 KB
  const int t = threadIdx.x;
  const int l = t & 63;
  const int w = t >> 6;
  const int sx = (l >> 1) & 3;      // read-side slot XOR
  const int o8 = __builtin_amdgcn_readfirstlane(w * 8);  // wave-uniform q base
  const long tile0 = (long)blockIdx.x * TN;
  const char* docsb = (const char*)docs;
  const float4* qn4 = (const float4*)qn;   // uniform-indexed -> s_load

  // Doc-stage: 16 issues/block/chunk; wave w handles i = w*4+jj.
  // Issue i: lane l -> doc (tile0 + i*16 + (l>>2)), piece (l&3)^((doc>>1)&3).
  unsigned dB[DLANE];   // per-lane source byte base (c-independent)
  int du[DLANE];        // wave-uniform LDS dest byte offset
  #pragma unroll
  for (int jj = 0; jj < DLANE; ++jj) {
    int i = w * DLANE + jj;
    long doc = tile0 + i * 16 + (l >> 2);
    if (doc >= N) doc = N - 1;
    unsigned piece = (unsigned)((l & 3) ^ (int)((doc >> 1) & 3));
    dB[jj] = (unsigned)(doc * (D * 4)) + piece * 16;
    du[jj] = __builtin_amdgcn_readfirstlane(i * 1024);
  }

#define STAGE(nxt, c) do {                                                   \
    unsigned co_ = (unsigned)((c) * 64);                                     \
    char* db_ = (char*)(&sD[(nxt)][0][0]);                                   \
    _Pragma("unroll")                                                        \
    for (int jj_ = 0; jj_ < DLANE; ++jj_) {                                  \
      __builtin_amdgcn_global_load_lds(                                      \
          (const AS1 void*)(docsb + (dB[jj_] + co_)),                        \
          (AS3 void*)(db_ + du[jj_]), 16, 0, 0);                             \
    }                                                                        \
  } while (0)

// One slot: doc ds_reads + ssq; prefetch next slot's q into QN; FMA with QC.
#define SLOT(S, QC, QN, PS) do {                                             \
    float4 dv[DLANE];                                                        \
    _Pragma("unroll")                                                        \
    for (int dj = 0; dj < DLANE; ++dj) {                                     \
      dv[dj] = sD[cur][l + dj * 64][(S) ^ sx];                               \
      ssq[dj] = fmaf(dv[dj].x, dv[dj].x, ssq[dj]);                           \
      ssq[dj] = fmaf(dv[dj].y, dv[dj].y, ssq[dj]);                           \
      ssq[dj] = fmaf(dv[dj].z, dv[dj].z, ssq[dj]);                           \
      ssq[dj] = fmaf(dv[dj].w, dv[dj].w, ssq[dj]);                           \
    }                                                                        \
    if ((PS) >= 0) {                                                         \
      _Pragma("unroll")                                                      \
      for (int qi = 0; qi < 8; ++qi)                                         \
        QN[qi] = qn4[(o8 + qi) * DF4 + qb + (PS)];                           \
    }                                                                        \
    _Pragma("unroll")                                                        \
    for (int qi = 0; qi < 8; ++qi) {                                         \
      float4 q4 = QC[qi];                                                    \
      _Pragma("unroll")                                                      \
      for (int dj = 0; dj < DLANE; ++dj) {                                   \
        acc[qi][dj] = fmaf(q4.x, dv[dj].x, acc[qi][dj]);                     \
        acc[qi][dj] = fmaf(q4.y, dv[dj].y, acc[qi][dj]);                     \
        acc[qi][dj] = fmaf(q4.z, dv[dj].z, acc[qi][dj]);                     \
        acc[qi][dj] = fmaf(q4.w, dv[dj].w, acc[qi][dj]);                     \
      }                                                                      \
    }                                                                        \
  } while (0)

  float acc[8][DLANE];
  #pragma unroll
  for (int i = 0; i < 8; ++i)
    #pragma unroll
    for (int j = 0; j < DLANE; ++j) acc[i][j] = 0.f;
  float ssq[DLANE];
  #pragma unroll
  for (int j = 0; j < DLANE; ++j) ssq[j] = 0.f;

  STAGE(0, 0);
  __syncthreads();          // chunk 0 landed
  int cur = 0;

  #pragma unroll 1
  for (int c = 0; c < NCHUNK; ++c) {
    if (c + 1 < NCHUNK) STAGE(cur ^ 1, c + 1);   // issue early, drain at barrier
    const int qb = c * 4;
    float4 qA[8], qB[8];
    #pragma unroll
    for (int qi = 0; qi < 8; ++qi) qA[qi] = qn4[(o8 + qi) * DF4 + qb];
    SLOT(0, qA, qB, 1);
    SLOT(1, qB, qA, 2);
    SLOT(2, qA, qB, 3);
    SLOT(3, qB, qA, -1);
    __syncthreads();        // all waves done with sD[cur]; chunk c+1 drained
    cur ^= 1;
  }
#undef SLOT
#undef STAGE

  #pragma unroll
  for (int dj = 0; dj < DLANE; ++dj) {
    long gd = tile0 + l + dj * 64;
    if (gd < N) {
      float rn = 1.0f / fmaxf(sqrtf(ssq[dj]), 1e-12f);
      #pragma unroll
      for (int qi = 0; qi < 8; ++qi)
        outS[(long)(o8 + qi) * N + gd] = acc[qi][dj] * rn;  // coalesced
    }
  }
}

// ---------------- top-k helpers ----------------
// ranks-before comparator: higher score wins; tie -> smaller index (lax.top_k stable)
__device__ __forceinline__ void insert10(float v, float p, float bs[10], float bi[10]) {
  bool last = (v > bs[9]) || (v == bs[9] && p < bi[9]);
  if (!last) return;
  #pragma unroll
  for (int j = 9; j >= 1; --j) {     // static indices only (no scratch)
    bool bj  = (v > bs[j])   || (v == bs[j]   && p < bi[j]);
    bool bjm = (v > bs[j-1]) || (v == bs[j-1] && p < bi[j-1]);
    float ns = bj ? (bjm ? bs[j-1] : v) : bs[j];
    float ni = bj ? (bjm ? bi[j-1] : p) : bi[j];
    bs[j] = ns; bi[j] = ni;
  }
  bool b0 = (v > bs[0]) || (v == bs[0] && p < bi[0]);
  if (b0) { bs[0] = v; bi[0] = p; }
}

// ---------------- K4: per-(row, segment) top-10 ----------------
__global__ __launch_bounds__(256) void k_topblk(const float* __restrict__ scores,
                                                float2* __restrict__ btop, int N) {
  const int row = blockIdx.y, seg = blockIdx.x, t = threadIdx.x;
  const int per = (N + NBK - 1) / NBK;
  const int s0 = seg * per;
  const int s1 = (s0 + per < N) ? (s0 + per) : N;
  const float* rp = scores + (long)row * N;
  float bs[10], bi[10];
  #pragma unroll
  for (int k = 0; k < 10; ++k) { bs[k] = -INFINITY; bi[k] = 2.0e9f; }
  for (int p = s0 + t; p < s1; p += 256) insert10(rp[p], (float)p, bs, bi);

  __shared__ float ms[256][10];
  __shared__ float mi[256][10];
  #pragma unroll
  for (int k = 0; k < 10; ++k) { ms[t][k] = bs[k]; mi[t][k] = bi[k]; }
  __syncthreads();
  for (int h = 128; h > 0; h >>= 1) {
    if (t < h) {
      float os[10], oi[10];
      int x = 0, y = 0;
      #pragma unroll
      for (int k = 0; k < 10; ++k) {
        float sx = ms[t][x], sy = ms[t + h][y];
        float ix = mi[t][x], iy = mi[t + h][y];
        bool ta = (sx > sy) || (sx == sy && ix < iy);
        os[k] = ta ? sx : sy; oi[k] = ta ? ix : iy;
        x += ta ? 1 : 0; y += ta ? 0 : 1;
      }
      #pragma unroll
      for (int k = 0; k < 10; ++k) { ms[t][k] = os[k]; mi[t][k] = oi[k]; }
    }
    __syncthreads();
  }
  if (t == 0) {
    #pragma unroll
    for (int k = 0; k < 10; ++k)
      btop[((long)row * NBK + seg) * 10 + k] = make_float2(ms[0][k], mi[0][k]);
  }
}

// ---------------- K5: final merge per row, write indices as float ----------------
__global__ __launch_bounds__(256) void k_topfinal(const float2* __restrict__ btop,
                                                  float* __restrict__ outIdx) {
  const int row = blockIdx.x, t = threadIdx.x;
  const int M = NBK * 10;   // 640 candidates
  float bs[10], bi[10];
  #pragma unroll
  for (int k = 0; k < 10; ++k) { bs[k] = -INFINITY; bi[k] = 2.0e9f; }
  for (int p = t; p < M; p += 256) {
    float2 c = btop[(long)row * M + p];
    insert10(c.x, c.y, bs, bi);
  }
  __shared__ float ms[256][10];
  __shared__ float mi[256][10];
  #pragma unroll
  for (int k = 0; k < 10; ++k) { ms[t][k] = bs[k]; mi[t][k] = bi[k]; }
  __syncthreads();
  for (int h = 128; h > 0; h >>= 1) {
    if (t < h) {
      float os[10], oi[10];
      int x = 0, y = 0;
      #pragma unroll
      for (int k = 0; k < 10; ++k) {
        float sx = ms[t][x], sy = ms[t + h][y];
        float ix = mi[t][x], iy = mi[t + h][y];
        bool ta = (sx > sy) || (sx == sy && ix < iy);
        os[k] = ta ? sx : sy; oi[k] = ta ? ix : iy;
        x += ta ? 1 : 0; y += ta ? 0 : 1;
      }
      #pragma unroll
      for (int k = 0; k < 10; ++k) { ms[t][k] = os[k]; mi[t][k] = oi[k]; }
    }
    __syncthreads();
  }
  if (t == 0) {
    #pragma unroll
    for (int k = 0; k < 10; ++k) outIdx[row * TOPK + k] = mi[0][k];
  }
}

extern "C" void kernel_launch(void* const* d_in, const int* in_sizes, int n_in,
                              void* d_out, int out_size, void* d_ws, size_t ws_size,
                              hipStream_t stream) {
  const float* q    = (const float*)d_in[0];   // [32,128,768]
  const float* docs = (const float*)d_in[1];   // [N,768]
  const float* W    = (const float*)d_in[2];   // [768,768]
  const float* bias = (const float*)d_in[3];   // [768]
  const int B = in_sizes[0] / (SEQ * D);       // 32
  const int N = in_sizes[1] / D;               // 500000

  float* out    = (float*)d_out;
  float* outIdx = out;                          // [B*10] indices as float
  float* outS   = out + (long)B * TOPK;         // [B][N] scores

  float*  qmean = (float*)d_ws;                 // B*D
  float*  qnorm = qmean + (long)B * D;          // B*D
  float2* btop  = (float2*)(qnorm + (long)B * D); // B*NBK*10 pairs

  dim3 g1(3, B);
  k_mean<<<g1, 256, 0, stream>>>(q, qmean);
  k_proj<<<B, 256, 0, stream>>>(qmean, W, bias, qnorm);
  int ntiles = (N + TN - 1) / TN;
  k_scores<<<ntiles, 256, 0, stream>>>(docs, qnorm, outS, N);
  dim3 g4(NBK, B);
  k_topblk<<<g4, 256, 0, stream>>>(outS, btop, N);
  k_topfinal<<<B, 256, 0, stream>>>(btop, outIdx);
}

// Round 10
// 657.262 us; speedup vs baseline: 1.1448x; 1.1448x over previous
//
#include <hip/hip_runtime.h>
#include <math.h>

#define D 768
#define DF4 192      // D/4
#define SEQ 128
#define TN 256       // docs per block tile (4 per lane)
#define DLANE 4
#define NCHUNK 48    // 16 floats (4 f4) per doc per chunk
#define NBK 64       // top-k blocks per row
#define TOPK 10

#define AS1 __attribute__((address_space(1)))
#define AS3 __attribute__((address_space(3)))

// ---------------- K1: mean over sequence ----------------
__global__ __launch_bounds__(256) void k_mean(const float* __restrict__ q,
                                              float* __restrict__ qmean) {
  int d = blockIdx.x * 256 + threadIdx.x;   // grid.x = 3 -> 768
  int b = blockIdx.y;
  if (d >= D) return;
  const float* p = q + (long)b * SEQ * D + d;
  float s = 0.f;
  #pragma unroll 8
  for (int i = 0; i < SEQ; ++i) s += p[(long)i * D];
  qmean[b * D + d] = s * (1.0f / SEQ);
}

// ---------------- K2: projection + bias + L2 normalize ----------------
__global__ __launch_bounds__(256) void k_proj(const float* __restrict__ qmean,
                                              const float* __restrict__ W,
                                              const float* __restrict__ bias,
                                              float* __restrict__ qnorm) {
  __shared__ float4 qm[DF4];
  __shared__ float red[256];
  int b = blockIdx.x, t = threadIdx.x;
  for (int i = t; i < DF4; i += 256) qm[i] = ((const float4*)qmean)[b * DF4 + i];
  __syncthreads();
  float myout[3];
  #pragma unroll
  for (int i = 0; i < 3; ++i) {
    int j = t + i * 256;
    const float4* wr = (const float4*)W + (long)j * DF4;
    float a0 = 0.f, a1 = 0.f, a2 = 0.f, a3 = 0.f;
    for (int kk = 0; kk < DF4; ++kk) {
      float4 w = wr[kk]; float4 qv = qm[kk];
      a0 = fmaf(w.x, qv.x, a0); a1 = fmaf(w.y, qv.y, a1);
      a2 = fmaf(w.z, qv.z, a2); a3 = fmaf(w.w, qv.w, a3);
    }
    myout[i] = (a0 + a1) + (a2 + a3) + bias[j];
  }
  float ss = myout[0]*myout[0] + myout[1]*myout[1] + myout[2]*myout[2];
  red[t] = ss;
  __syncthreads();
  for (int h = 128; h > 0; h >>= 1) {
    if (t < h) red[t] += red[t + h];
    __syncthreads();
  }
  float rn = 1.0f / fmaxf(sqrtf(red[0]), 1e-12f);
  #pragma unroll
  for (int i = 0; i < 3; ++i) {
    int j = t + i * 256;
    qnorm[b * D + j] = myout[i] * rn;
  }
}

// ---------------- K3: cosine scores (the big one) ----------------
// r10 = the clean double-buffer experiment. Evidence base:
//  - q-delivery MUST be LDS broadcast: r6 (LDS-q, 590us) vs r5/r9 (SGPR-q,
//    1425/700us) — SMEM+DS share lgkmcnt out-of-order -> serializing drains.
//  - Occupancy 4 blocks/CU matters: r8 (3 blk/CU) = +17% vs r6.
//  - Staging must be >=64B contiguous segments per doc (r7's 16B gather
//    = +37%); r8's 64B-segment + (doc>>1)&3 involution verified conflict-free
//    (2 lanes/bank-quad per 16-lane phase = free, m136).
//  - r6's residual over the 352us LDS-read pillar is exposed single-buffered
//    staging (stage->drain->compute each chunk). r10 double-buffers: stage
//    chunk c+1 BEFORE computing chunk c, ONE barrier per chunk; the barrier's
//    vmcnt(0) lands a full compute phase (~2300cyc) after issue >> HBM ~900.
//  - LDS 2x16 (docs) + 2x2 (q) = 36 KB -> 4 blocks/CU, 16 waves resident.
//  - Natural VGPR alloc (~80 live): launch_bounds(256,{2,3,4}) pins 64 VGPR
//    and spills 1.5-7 GB (r1/r3/r4 measured); bare bounds allocs naturally.
__global__ __launch_bounds__(256) __attribute__((amdgpu_waves_per_eu(2, 4)))
void k_scores(const float* __restrict__ docs,
              const float* __restrict__ qn,
              float* __restrict__ outS, int N) {
  __shared__ float4 sD[2][TN][4];   // 2 x 16 KB
  __shared__ float4 sQ[2][32][4];   // 2 x 2 KB
  const int t = threadIdx.x;
  const int l = t & 63;
  const int w = t >> 6;
  const int sx = (l >> 1) & 3;      // read-side slot XOR
  const long tile0 = (long)blockIdx.x * TN;
  const char* docsb = (const char*)docs;
  const char* qnb = (const char*)qn;

  // Doc-stage: 16 issues/block/chunk; wave w handles i = w*4+jj.
  // Issue i: lane l -> doc (tile0 + i*16 + (l>>2)), piece (l&3)^((doc>>1)&3).
  // 16 docs x 64 B contiguous segments per wave-inst (coalesced, r8-proven).
  unsigned dB[DLANE];   // per-lane source byte base (c-independent)
  int du[DLANE];        // wave-uniform LDS dest byte offset
  #pragma unroll
  for (int jj = 0; jj < DLANE; ++jj) {
    int i = w * DLANE + jj;
    long doc = tile0 + i * 16 + (l >> 2);
    if (doc >= N) doc = N - 1;
    unsigned piece = (unsigned)((l & 3) ^ (int)((doc >> 1) & 3));
    dB[jj] = (unsigned)(doc * (D * 4)) + piece * 16;
    du[jj] = __builtin_amdgcn_readfirstlane(i * 1024);
  }
  // q-stage: 2 issues (waves 0,1): lane l -> row w*16+(l>>2), piece l&3.
  // Linear dest (sQ row*64 + piece*16); broadcast reads never conflict.
  const unsigned qB = (unsigned)(((w & 1) * 16 + (l >> 2)) * (D * 4))
                    + (unsigned)((l & 3) * 16);
  const int qdu = __builtin_amdgcn_readfirstlane((w & 1) * 1024);

#define STAGE(nxt, c) do {                                                   \
    unsigned co_ = (unsigned)((c) * 64);                                     \
    char* db_ = (char*)(&sD[(nxt)][0][0]);                                   \
    _Pragma("unroll")                                                        \
    for (int jj_ = 0; jj_ < DLANE; ++jj_) {                                  \
      __builtin_amdgcn_global_load_lds(                                      \
          (const AS1 void*)(docsb + (dB[jj_] + co_)),                        \
          (AS3 void*)(db_ + du[jj_]), 16, 0, 0);                             \
    }                                                                        \
    if (w < 2) {                                                             \
      __builtin_amdgcn_global_load_lds(                                      \
          (const AS1 void*)(qnb + (qB + co_)),                               \
          (AS3 void*)((char*)(&sQ[(nxt)][0][0]) + qdu), 16, 0, 0);           \
    }                                                                        \
  } while (0)

  float acc[8][DLANE];
  #pragma unroll
  for (int i = 0; i < 8; ++i)
    #pragma unroll
    for (int j = 0; j < DLANE; ++j) acc[i][j] = 0.f;
  float ssq[DLANE];
  #pragma unroll
  for (int j = 0; j < DLANE; ++j) ssq[j] = 0.f;

  STAGE(0, 0);
  __syncthreads();          // chunk 0 landed
  int cur = 0;

  #pragma unroll 1
  for (int c = 0; c < NCHUNK; ++c) {
    if (c + 1 < NCHUNK) STAGE(cur ^ 1, c + 1);   // issue early, drain at barrier
    #pragma unroll
    for (int s = 0; s < 4; ++s) {
      float4 dv[DLANE];
      #pragma unroll
      for (int dj = 0; dj < DLANE; ++dj) {
        dv[dj] = sD[cur][l + dj * 64][s ^ sx];
        ssq[dj] = fmaf(dv[dj].x, dv[dj].x, ssq[dj]);
        ssq[dj] = fmaf(dv[dj].y, dv[dj].y, ssq[dj]);
        ssq[dj] = fmaf(dv[dj].z, dv[dj].z, ssq[dj]);
        ssq[dj] = fmaf(dv[dj].w, dv[dj].w, ssq[dj]);
      }
      #pragma unroll
      for (int qi = 0; qi < 8; ++qi) {
        float4 q4 = sQ[cur][w * 8 + qi][s];      // uniform addr -> broadcast
        #pragma unroll
        for (int dj = 0; dj < DLANE; ++dj) {
          acc[qi][dj] = fmaf(q4.x, dv[dj].x, acc[qi][dj]);
          acc[qi][dj] = fmaf(q4.y, dv[dj].y, acc[qi][dj]);
          acc[qi][dj] = fmaf(q4.z, dv[dj].z, acc[qi][dj]);
          acc[qi][dj] = fmaf(q4.w, dv[dj].w, acc[qi][dj]);
        }
      }
    }
    __syncthreads();        // all waves done with sD/sQ[cur]; chunk c+1 drained
    cur ^= 1;
  }
#undef STAGE

  #pragma unroll
  for (int dj = 0; dj < DLANE; ++dj) {
    long gd = tile0 + l + dj * 64;
    if (gd < N) {
      float rn = 1.0f / fmaxf(sqrtf(ssq[dj]), 1e-12f);
      #pragma unroll
      for (int qi = 0; qi < 8; ++qi)
        outS[(long)(w * 8 + qi) * N + gd] = acc[qi][dj] * rn;  // coalesced
    }
  }
}

// ---------------- top-k helpers ----------------
// ranks-before comparator: higher score wins; tie -> smaller index (lax.top_k stable)
__device__ __forceinline__ void insert10(float v, float p, float bs[10], float bi[10]) {
  bool last = (v > bs[9]) || (v == bs[9] && p < bi[9]);
  if (!last) return;
  #pragma unroll
  for (int j = 9; j >= 1; --j) {     // static indices only (no scratch)
    bool bj  = (v > bs[j])   || (v == bs[j]   && p < bi[j]);
    bool bjm = (v > bs[j-1]) || (v == bs[j-1] && p < bi[j-1]);
    float ns = bj ? (bjm ? bs[j-1] : v) : bs[j];
    float ni = bj ? (bjm ? bi[j-1] : p) : bi[j];
    bs[j] = ns; bi[j] = ni;
  }
  bool b0 = (v > bs[0]) || (v == bs[0] && p < bi[0]);
  if (b0) { bs[0] = v; bi[0] = p; }
}

// ---------------- K4: per-(row, segment) top-10 ----------------
__global__ __launch_bounds__(256) void k_topblk(const float* __restrict__ scores,
                                                float2* __restrict__ btop, int N) {
  const int row = blockIdx.y, seg = blockIdx.x, t = threadIdx.x;
  const int per = (N + NBK - 1) / NBK;
  const int s0 = seg * per;
  const int s1 = (s0 + per < N) ? (s0 + per) : N;
  const float* rp = scores + (long)row * N;
  float bs[10], bi[10];
  #pragma unroll
  for (int k = 0; k < 10; ++k) { bs[k] = -INFINITY; bi[k] = 2.0e9f; }
  for (int p = s0 + t; p < s1; p += 256) insert10(rp[p], (float)p, bs, bi);

  __shared__ float ms[256][10];
  __shared__ float mi[256][10];
  #pragma unroll
  for (int k = 0; k < 10; ++k) { ms[t][k] = bs[k]; mi[t][k] = bi[k]; }
  __syncthreads();
  for (int h = 128; h > 0; h >>= 1) {
    if (t < h) {
      float os[10], oi[10];
      int x = 0, y = 0;
      #pragma unroll
      for (int k = 0; k < 10; ++k) {
        float sx = ms[t][x], sy = ms[t + h][y];
        float ix = mi[t][x], iy = mi[t + h][y];
        bool ta = (sx > sy) || (sx == sy && ix < iy);
        os[k] = ta ? sx : sy; oi[k] = ta ? ix : iy;
        x += ta ? 1 : 0; y += ta ? 0 : 1;
      }
      #pragma unroll
      for (int k = 0; k < 10; ++k) { ms[t][k] = os[k]; mi[t][k] = oi[k]; }
    }
    __syncthreads();
  }
  if (t == 0) {
    #pragma unroll
    for (int k = 0; k < 10; ++k)
      btop[((long)row * NBK + seg) * 10 + k] = make_float2(ms[0][k], mi[0][k]);
  }
}

// ---------------- K5: final merge per row, write indices as float ----------------
__global__ __launch_bounds__(256) void k_topfinal(const float2* __restrict__ btop,
                                                  float* __restrict__ outIdx) {
  const int row = blockIdx.x, t = threadIdx.x;
  const int M = NBK * 10;   // 640 candidates
  float bs[10], bi[10];
  #pragma unroll
  for (int k = 0; k < 10; ++k) { bs[k] = -INFINITY; bi[k] = 2.0e9f; }
  for (int p = t; p < M; p += 256) {
    float2 c = btop[(long)row * M + p];
    insert10(c.x, c.y, bs, bi);
  }
  __shared__ float ms[256][10];
  __shared__ float mi[256][10];
  #pragma unroll
  for (int k = 0; k < 10; ++k) { ms[t][k] = bs[k]; mi[t][k] = bi[k]; }
  __syncthreads();
  for (int h = 128; h > 0; h >>= 1) {
    if (t < h) {
      float os[10], oi[10];
      int x = 0, y = 0;
      #pragma unroll
      for (int k = 0; k < 10; ++k) {
        float sx = ms[t][x], sy = ms[t + h][y];
        float ix = mi[t][x], iy = mi[t + h][y];
        bool ta = (sx > sy) || (sx == sy && ix < iy);
        os[k] = ta ? sx : sy; oi[k] = ta ? ix : iy;
        x += ta ? 1 : 0; y += ta ? 0 : 1;
      }
      #pragma unroll
      for (int k = 0; k < 10; ++k) { ms[t][k] = os[k]; mi[t][k] = oi[k]; }
    }
    __syncthreads();
  }
  if (t == 0) {
    #pragma unroll
    for (int k = 0; k < 10; ++k) outIdx[row * TOPK + k] = mi[0][k];
  }
}

extern "C" void kernel_launch(void* const* d_in, const int* in_sizes, int n_in,
                              void* d_out, int out_size, void* d_ws, size_t ws_size,
                              hipStream_t stream) {
  const float* q    = (const float*)d_in[0];   // [32,128,768]
  const float* docs = (const float*)d_in[1];   // [N,768]
  const float* W    = (const float*)d_in[2];   // [768,768]
  const float* bias = (const float*)d_in[3];   // [768]
  const int B = in_sizes[0] / (SEQ * D);       // 32
  const int N = in_sizes[1] / D;               // 500000

  float* out    = (float*)d_out;
  float* outIdx = out;                          // [B*10] indices as float
  float* outS   = out + (long)B * TOPK;         // [B][N] scores

  float*  qmean = (float*)d_ws;                 // B*D
  float*  qnorm = qmean + (long)B * D;          // B*D
  float2* btop  = (float2*)(qnorm + (long)B * D); // B*NBK*10 pairs

  dim3 g1(3, B);
  k_mean<<<g1, 256, 0, stream>>>(q, qmean);
  k_proj<<<B, 256, 0, stream>>>(qmean, W, bias, qnorm);
  int ntiles = (N + TN - 1) / TN;
  k_scores<<<ntiles, 256, 0, stream>>>(docs, qnorm, outS, N);
  dim3 g4(NBK, B);
  k_topblk<<<g4, 256, 0, stream>>>(outS, btop, N);
  k_topfinal<<<B, 256, 0, stream>>>(btop, outIdx);
}